// Round 3
// baseline (1264.925 us; speedup 1.0000x reference)
//
#include <hip/hip_runtime.h>

typedef float v2 __attribute__((ext_vector_type(2)));

#define BLK 256

static __device__ __forceinline__ v2 mkv2(float a, float b){ v2 r; r.x = a; r.y = b; return r; }

template<int N>
static __device__ __forceinline__ float dotN(const v2* __restrict__ w, const v2* in){
    v2 a = {0.f, 0.f};
    #pragma unroll
    for (int k = 0; k < N; ++k) a += in[k] * w[k];
    return a.x + a.y;
}

// Volatile LDS read: cannot be rematerialized -> value must stay in VGPRs.
static __device__ __forceinline__ v2 ldv(const v2* p){
    const volatile float* q = (const volatile float*)p;
    return mkv2(q[0], q[1]);
}

// Pad sW1 (41x41), sW2 (41x41), sW3 (22x41) to row-stride 42 with zero in col 41,
// so packed (v2) weight loads are 8B-aligned and the pair count is uniform (21).
__global__ void prep_pad(const float* __restrict__ sW1,
                         const float* __restrict__ sW2,
                         const float* __restrict__ sW3,
                         float* __restrict__ wp)
{
    int i = blockIdx.x * 256 + threadIdx.x;
    if (i >= 4368) return;
    float v;
    if (i < 1722) {
        int o = i / 42, j = i - o * 42;
        v = (j < 41) ? sW1[o * 41 + j] : 0.f;
    } else if (i < 3444) {
        int k = i - 1722; int o = k / 42, j = k - o * 42;
        v = (j < 41) ? sW2[o * 41 + j] : 0.f;
    } else {
        int k = i - 3444; int o = k / 42, j = k - o * 42;
        v = (j < 41) ? sW3[o * 41 + j] : 0.f;
    }
    wp[i] = v;
}

__global__ __launch_bounds__(BLK, 3) void ran_fused(
    const float* __restrict__ x,
    const float* __restrict__ bW1, const float* __restrict__ bb1,
    const float* __restrict__ bW2, const float* __restrict__ bb2,
    const float* __restrict__ bW3, const float* __restrict__ bb3,
    const float* __restrict__ sWp,   // padded: sW1p@0, sW2p@1722, sW3p@3444, row stride 42
    const float* __restrict__ sb1, const float* __restrict__ sb2,
    const float* __restrict__ sb3,
    float* __restrict__ out)
{
    __shared__ v2    xt[BLK * 21];   // 256 rows x 42 floats (40 data + 2 pad), 8B units
    __shared__ float ia[10 * BLK];   // iab via LDS: allows runtime slot index
    const int t    = threadIdx.x;
    const int row0 = blockIdx.x * BLK;
    const float4* __restrict__ xg = (const float4*)x;

    // ---- chunk 0: x_iabs = x[:, 0:40] (coalesced float4 -> LDS) ----
    #pragma unroll
    for (int i = 0; i < 10; ++i) {
        int f = t + BLK * i;              // 0..2559 over the 256x10 float4 tile
        int r = f / 10, c = f - r * 10;
        float4 v = xg[(row0 + r) * 110 + c];
        xt[r * 21 + 2 * c]     = mkv2(v.x, v.y);
        xt[r * 21 + 2 * c + 1] = mkv2(v.z, v.w);
    }
    __syncthreads();

    v2 xr[20];
    #pragma unroll
    for (int k = 0; k < 20; ++k) xr[k] = ldv(&xt[t * 21 + k]);

    // ---- big MLP: 40 -> 40 -> 40 -> 10, softmax ----
    v2 h1[20];
    #pragma unroll
    for (int o = 0; o < 20; ++o) {
        float r0 = fmaxf(bb1[2*o]   + dotN<20>((const v2*)(bW1 + (2*o)*40),   xr), 0.f);
        float r1 = fmaxf(bb1[2*o+1] + dotN<20>((const v2*)(bW1 + (2*o+1)*40), xr), 0.f);
        h1[o] = mkv2(r0, r1);
    }
    v2 h2[20];
    #pragma unroll
    for (int o = 0; o < 20; ++o) {
        float r0 = fmaxf(bb2[2*o]   + dotN<20>((const v2*)(bW2 + (2*o)*40),   h1), 0.f);
        float r1 = fmaxf(bb2[2*o+1] + dotN<20>((const v2*)(bW2 + (2*o+1)*40), h1), 0.f);
        h2[o] = mkv2(r0, r1);
    }
    float lg[10];
    #pragma unroll
    for (int o = 0; o < 10; ++o)
        lg[o] = bb3[o] + dotN<20>((const v2*)(bW3 + o * 40), h2);

    float mx = lg[0];
    #pragma unroll
    for (int o = 1; o < 10; ++o) mx = fmaxf(mx, lg[o]);
    float ssum = 0.f;
    float ev[10];
    #pragma unroll
    for (int o = 0; o < 10; ++o) { ev[o] = __expf(lg[o] - mx); ssum += ev[o]; }
    float rs = __fdividef(1.f, ssum);
    #pragma unroll
    for (int o = 0; o < 10; ++o) ia[o * BLK + t] = ev[o] * rs;  // own-thread slot, no barrier needed

    // ---- small MLP per slot: [x_ues_s(40), iab_s] -> 41 -> 41 -> 22 softmax * iab_s ----
    for (int s = 0; s < 10; ++s) {
        __syncthreads();                 // xt free (previous readers done)
        #pragma unroll
        for (int i = 0; i < 10; ++i) {
            int f = t + BLK * i;
            int r = f / 10, c = f - r * 10;
            float4 v = xg[(row0 + r) * 110 + 10 + s * 10 + c];
            xt[r * 21 + 2 * c]     = mkv2(v.x, v.y);
            xt[r * 21 + 2 * c + 1] = mkv2(v.z, v.w);
        }
        __syncthreads();

        float iv = ia[s * BLK + t];
        v2 xs[21];
        #pragma unroll
        for (int k = 0; k < 20; ++k) xs[k] = ldv(&xt[t * 21 + k]);
        xs[20] = mkv2(iv, 0.f);
        __syncthreads();                 // xs reads done; xt reusable as out tile

        v2 g1[21];
        #pragma unroll
        for (int o = 0; o < 20; ++o) {
            float r0 = fmaxf(sb1[2*o]   + dotN<21>((const v2*)(sWp + (2*o)*42),   xs), 0.f);
            float r1 = fmaxf(sb1[2*o+1] + dotN<21>((const v2*)(sWp + (2*o+1)*42), xs), 0.f);
            g1[o] = mkv2(r0, r1);
        }
        g1[20] = mkv2(fmaxf(sb1[40] + dotN<21>((const v2*)(sWp + 40*42), xs), 0.f), 0.f);

        v2 g2[21];
        #pragma unroll
        for (int o = 0; o < 20; ++o) {
            float r0 = fmaxf(sb2[2*o]   + dotN<21>((const v2*)(sWp + 1722 + (2*o)*42),   g1), 0.f);
            float r1 = fmaxf(sb2[2*o+1] + dotN<21>((const v2*)(sWp + 1722 + (2*o+1)*42), g1), 0.f);
            g2[o] = mkv2(r0, r1);
        }
        g2[20] = mkv2(fmaxf(sb2[40] + dotN<21>((const v2*)(sWp + 1722 + 40*42), g1), 0.f), 0.f);

        float l3[22];
        #pragma unroll
        for (int o = 0; o < 22; ++o)
            l3[o] = sb3[o] + dotN<21>((const v2*)(sWp + 3444 + o * 42), g2);

        float m2 = l3[0];
        #pragma unroll
        for (int o = 1; o < 22; ++o) m2 = fmaxf(m2, l3[o]);
        float s2 = 0.f;
        float e2[22];
        #pragma unroll
        for (int o = 0; o < 22; ++o) { e2[o] = __expf(l3[o] - m2); s2 += e2[o]; }
        float sc = __fdividef(iv, s2);   // iab_s / sum

        // stage 22 outputs in xt (cols 0..10 as v2), then coalesced store
        #pragma unroll
        for (int c = 0; c < 11; ++c) xt[t * 21 + c] = mkv2(e2[2*c] * sc, e2[2*c+1] * sc);
        __syncthreads();

        float2* __restrict__ og = (float2*)out;
        #pragma unroll
        for (int i = 0; i < 11; ++i) {
            int f = t + BLK * i;          // 0..2815 over the 256x11 float2 tile
            int r = f / 11, c = f - r * 11;
            v2 v = xt[r * 21 + c];
            og[(row0 + r) * 110 + s * 11 + c] = make_float2(v.x, v.y);
        }
    }
}

extern "C" void kernel_launch(void* const* d_in, const int* in_sizes, int n_in,
                              void* d_out, int out_size, void* d_ws, size_t ws_size,
                              hipStream_t stream)
{
    (void)n_in; (void)out_size; (void)ws_size;
    const float* x   = (const float*)d_in[0];
    const float* bW1 = (const float*)d_in[1];
    const float* bb1 = (const float*)d_in[2];
    const float* bW2 = (const float*)d_in[3];
    const float* bb2 = (const float*)d_in[4];
    const float* bW3 = (const float*)d_in[5];
    const float* bb3 = (const float*)d_in[6];
    const float* sW1 = (const float*)d_in[7];
    const float* sb1 = (const float*)d_in[8];
    const float* sW2 = (const float*)d_in[9];
    const float* sb2 = (const float*)d_in[10];
    const float* sW3 = (const float*)d_in[11];
    const float* sb3 = (const float*)d_in[12];
    float* out = (float*)d_out;
    float* wp  = (float*)d_ws;

    prep_pad<<<18, 256, 0, stream>>>(sW1, sW2, sW3, wp);

    const int rows = in_sizes[0] / 440;           // 262144
    ran_fused<<<rows / BLK, BLK, 0, stream>>>(x, bW1, bb1, bW2, bb2, bW3, bb3,
                                              wp, sb1, sb2, sb3, out);
}

// Round 4
// 867.662 us; speedup vs baseline: 1.4579x; 1.4579x over previous
//
#include <hip/hip_runtime.h>

typedef __attribute__((ext_vector_type(4))) float f32x4;
typedef __attribute__((ext_vector_type(8))) short s16x8;

#define ROWS 32        // rows per block (1 wave)
#define XDIM 440
#define ODIM 220
#define ASTR 68        // Act row stride in floats (68: 2-way LDS conflicts only)

// ws layout (bytes):
//   WH  : ushort[240*64] @ 0       (bf16 hi, padded [N][64])
//   WL  : ushort[240*64] @ 30720   (bf16 lo)
//   BIAS: float [240]    @ 61440   (padded; softmax pads = -1e30)
// weight-row map: [0..47]=bW1 [48..95]=bW2 [96..111]=bW3
//                 [112..159]=sW1 [160..207]=sW2 [208..239]=sW3

__device__ __forceinline__ unsigned short bf_rne(float f){
    unsigned u = __builtin_bit_cast(unsigned, f);
    unsigned r = (u + 0x7FFFu + ((u >> 16) & 1u)) >> 16;
    return (unsigned short)r;
}

__global__ void prep_w(const float* __restrict__ bW1, const float* __restrict__ bW2,
                       const float* __restrict__ bW3, const float* __restrict__ sW1,
                       const float* __restrict__ sW2, const float* __restrict__ sW3,
                       const float* __restrict__ bb1, const float* __restrict__ bb2,
                       const float* __restrict__ bb3, const float* __restrict__ sb1,
                       const float* __restrict__ sb2, const float* __restrict__ sb3,
                       unsigned short* __restrict__ WH, unsigned short* __restrict__ WL,
                       float* __restrict__ BIAS)
{
    int i = blockIdx.x * 256 + threadIdx.x;
    if (i < 15360) {
        int n = i >> 6, k = i & 63;
        float w = 0.f;
        if      (n < 48)  { int r = n;     if (r < 40 && k < 40) w = bW1[r*40+k]; }
        else if (n < 96)  { int r = n-48;  if (r < 40 && k < 40) w = bW2[r*40+k]; }
        else if (n < 112) { int r = n-96;  if (r < 10 && k < 40) w = bW3[r*40+k]; }
        else if (n < 160) { int r = n-112; if (r < 41 && k < 41) w = sW1[r*41+k]; }
        else if (n < 208) { int r = n-160; if (r < 41 && k < 41) w = sW2[r*41+k]; }
        else              { int r = n-208; if (r < 22 && k < 41) w = sW3[r*41+k]; }
        unsigned short h = bf_rne(w);
        float hf = __builtin_bit_cast(float, ((unsigned)h) << 16);
        unsigned short lo = bf_rne(w - hf);
        WH[i] = h; WL[i] = lo;
    } else if (i < 15600) {
        int n = i - 15360;
        float b;
        if      (n < 48)  b = (n     < 40) ? bb1[n]     : 0.f;
        else if (n < 96)  b = (n-48  < 40) ? bb2[n-48]  : 0.f;
        else if (n < 112) b = (n-96  < 10) ? bb3[n-96]  : -1e30f;
        else if (n < 160) b = (n-112 < 41) ? sb1[n-112] : 0.f;
        else if (n < 208) b = (n-160 < 41) ? sb2[n-160] : 0.f;
        else              b = (n-208 < 22) ? sb3[n-208] : -1e30f;
        BIAS[n] = b;
    }
}

// split fp32 -> (hi bf16, lo bf16); v - hi is exact (Sterbenz), so total
// representation error <= ~2^-17 relative.
__device__ __forceinline__ void split8(const float* v, s16x8& h, s16x8& l){
    #pragma unroll
    for (int j = 0; j < 8; ++j) {
        unsigned u  = __builtin_bit_cast(unsigned, v[j]);
        unsigned rh = (u + 0x7FFFu + ((u >> 16) & 1u)) >> 16;
        float    hf = __builtin_bit_cast(float, rh << 16);
        float    lf = v[j] - hf;
        unsigned ul = __builtin_bit_cast(unsigned, lf);
        unsigned rl = (ul + 0x7FFFu + ((ul >> 16) & 1u)) >> 16;
        h[j] = (short)rh;
        l[j] = (short)rl;
    }
}

// D += A*B with split operands: AhBh + AhBl + AlBh (drop AlBl, ~2^-18)
__device__ __forceinline__ f32x4 mm3(s16x8 ah, s16x8 al, s16x8 bh, s16x8 bl, f32x4 c){
    c = __builtin_amdgcn_mfma_f32_16x16x32_bf16(ah, bh, c, 0, 0, 0);
    c = __builtin_amdgcn_mfma_f32_16x16x32_bf16(ah, bl, c, 0, 0, 0);
    c = __builtin_amdgcn_mfma_f32_16x16x32_bf16(al, bh, c, 0, 0, 0);
    return c;
}

__device__ __forceinline__ s16x8 ld8u(const unsigned short* p){
    return *(const s16x8*)p;
}

__global__ __launch_bounds__(64, 4) void ran_mfma(
    const float* __restrict__ x,
    const unsigned short* __restrict__ WH,
    const unsigned short* __restrict__ WL,
    const float* __restrict__ BIAS,
    float* __restrict__ out)
{
    __shared__ float Act[ROWS * ASTR];   // inter-layer activations, fp32, K-padded
    __shared__ float ia[ROWS * 10];      // iab, [row][class], stride 10 (conflict-free)

    const int l  = threadIdx.x;
    const int q  = l >> 4;
    const int li = l & 15;
    const int R0 = blockIdx.x * ROWS;

    // zero Act cols 48..63 once (never written by D-stores; read as K-pad)
    {
        int r = l >> 1, c0 = 48 + (l & 1) * 8;
        #pragma unroll
        for (int j = 0; j < 8; ++j) Act[r * ASTR + c0 + j] = 0.f;
    }
    __syncthreads();

    // ================= BIG NET =================
    // ---- L1: x[:,0:40] -> Act cols 0..47 ----
    {
        s16x8 bh[3][2], bl[3][2]; float bs[3];
        #pragma unroll
        for (int nt = 0; nt < 3; ++nt) {
            bs[nt] = BIAS[nt*16 + li];
            #pragma unroll
            for (int ks = 0; ks < 2; ++ks) {
                int wi = (nt*16 + li) * 64 + ks*32 + q*8;
                bh[nt][ks] = ld8u(WH + wi);
                bl[nt][ks] = ld8u(WL + wi);
            }
        }
        #pragma unroll
        for (int t = 0; t < 2; ++t) {
            const float* xp = x + (size_t)(R0 + t*16 + li) * XDIM;
            float a0[8], a1[8];
            *(float4*)(a0)   = *(const float4*)(xp + q*8);
            *(float4*)(a0+4) = *(const float4*)(xp + q*8 + 4);
            if (q == 0) {
                *(float4*)(a1)   = *(const float4*)(xp + 32);
                *(float4*)(a1+4) = *(const float4*)(xp + 36);
            } else {
                #pragma unroll
                for (int j = 0; j < 8; ++j) a1[j] = 0.f;
            }
            s16x8 ah0, al0, ah1, al1;
            split8(a0, ah0, al0); split8(a1, ah1, al1);
            #pragma unroll
            for (int nt = 0; nt < 3; ++nt) {
                f32x4 acc = {bs[nt], bs[nt], bs[nt], bs[nt]};
                acc = mm3(ah0, al0, bh[nt][0], bl[nt][0], acc);
                acc = mm3(ah1, al1, bh[nt][1], bl[nt][1], acc);
                #pragma unroll
                for (int r = 0; r < 4; ++r)
                    Act[(t*16 + q*4 + r) * ASTR + nt*16 + li] = fmaxf(acc[r], 0.f);
            }
        }
    }
    __syncthreads();

    // ---- L2: Act -> Act ----
    {
        s16x8 bh[3][2], bl[3][2]; float bs[3];
        #pragma unroll
        for (int nt = 0; nt < 3; ++nt) {
            bs[nt] = BIAS[48 + nt*16 + li];
            #pragma unroll
            for (int ks = 0; ks < 2; ++ks) {
                int wi = (48 + nt*16 + li) * 64 + ks*32 + q*8;
                bh[nt][ks] = ld8u(WH + wi);
                bl[nt][ks] = ld8u(WL + wi);
            }
        }
        #pragma unroll
        for (int t = 0; t < 2; ++t) {
            const float* ap = Act + (t*16 + li) * ASTR;
            float a0[8], a1[8];
            *(float4*)(a0)   = *(const float4*)(ap + q*8);
            *(float4*)(a0+4) = *(const float4*)(ap + q*8 + 4);
            *(float4*)(a1)   = *(const float4*)(ap + 32 + q*8);
            *(float4*)(a1+4) = *(const float4*)(ap + 32 + q*8 + 4);
            s16x8 ah0, al0, ah1, al1;
            split8(a0, ah0, al0); split8(a1, ah1, al1);
            #pragma unroll
            for (int nt = 0; nt < 3; ++nt) {
                f32x4 acc = {bs[nt], bs[nt], bs[nt], bs[nt]};
                acc = mm3(ah0, al0, bh[nt][0], bl[nt][0], acc);
                acc = mm3(ah1, al1, bh[nt][1], bl[nt][1], acc);
                #pragma unroll
                for (int r = 0; r < 4; ++r)
                    Act[(t*16 + q*4 + r) * ASTR + nt*16 + li] = fmaxf(acc[r], 0.f);
            }
        }
    }
    __syncthreads();

    // ---- L3 + softmax -> ia ----
    {
        s16x8 bh[2], bl[2];
        float bs = BIAS[96 + li];
        #pragma unroll
        for (int ks = 0; ks < 2; ++ks) {
            int wi = (96 + li) * 64 + ks*32 + q*8;
            bh[ks] = ld8u(WH + wi);
            bl[ks] = ld8u(WL + wi);
        }
        #pragma unroll
        for (int t = 0; t < 2; ++t) {
            const float* ap = Act + (t*16 + li) * ASTR;
            float a0[8], a1[8];
            *(float4*)(a0)   = *(const float4*)(ap + q*8);
            *(float4*)(a0+4) = *(const float4*)(ap + q*8 + 4);
            *(float4*)(a1)   = *(const float4*)(ap + 32 + q*8);
            *(float4*)(a1+4) = *(const float4*)(ap + 32 + q*8 + 4);
            s16x8 ah0, al0, ah1, al1;
            split8(a0, ah0, al0); split8(a1, ah1, al1);
            f32x4 acc = {bs, bs, bs, bs};
            acc = mm3(ah0, al0, bh[0], bl[0], acc);
            acc = mm3(ah1, al1, bh[1], bl[1], acc);
            #pragma unroll
            for (int r = 0; r < 4; ++r) {
                float v = acc[r];
                float m = v;
                m = fmaxf(m, __shfl_xor(m, 1));
                m = fmaxf(m, __shfl_xor(m, 2));
                m = fmaxf(m, __shfl_xor(m, 4));
                m = fmaxf(m, __shfl_xor(m, 8));
                float e = __expf(v - m);
                float sum = e;
                sum += __shfl_xor(sum, 1);
                sum += __shfl_xor(sum, 2);
                sum += __shfl_xor(sum, 4);
                sum += __shfl_xor(sum, 8);
                float p = __fdividef(e, sum);
                if (li < 10) ia[(t*16 + q*4 + r) * 10 + li] = p;
            }
        }
    }
    __syncthreads();

    // ================= SMALL NET, per slot =================
    for (int s = 0; s < 10; ++s) {
        // ---- L1: [x_ues(40), iab] -> Act ----
        {
            s16x8 bh[3][2], bl[3][2]; float bs[3];
            #pragma unroll
            for (int nt = 0; nt < 3; ++nt) {
                bs[nt] = BIAS[112 + nt*16 + li];
                #pragma unroll
                for (int ks = 0; ks < 2; ++ks) {
                    int wi = (112 + nt*16 + li) * 64 + ks*32 + q*8;
                    bh[nt][ks] = ld8u(WH + wi);
                    bl[nt][ks] = ld8u(WL + wi);
                }
            }
            #pragma unroll
            for (int t = 0; t < 2; ++t) {
                const float* xp = x + (size_t)(R0 + t*16 + li) * XDIM + 40 + s*40;
                float iv = ia[(t*16 + li) * 10 + s];
                float a0[8], a1[8];
                *(float4*)(a0)   = *(const float4*)(xp + q*8);
                *(float4*)(a0+4) = *(const float4*)(xp + q*8 + 4);
                if (q == 0) {
                    *(float4*)(a1)   = *(const float4*)(xp + 32);
                    *(float4*)(a1+4) = *(const float4*)(xp + 36);
                } else {
                    #pragma unroll
                    for (int j = 0; j < 8; ++j) a1[j] = 0.f;
                    if (q == 1) a1[0] = iv;     // k = 40: iab input
                }
                s16x8 ah0, al0, ah1, al1;
                split8(a0, ah0, al0); split8(a1, ah1, al1);
                #pragma unroll
                for (int nt = 0; nt < 3; ++nt) {
                    f32x4 acc = {bs[nt], bs[nt], bs[nt], bs[nt]};
                    acc = mm3(ah0, al0, bh[nt][0], bl[nt][0], acc);
                    acc = mm3(ah1, al1, bh[nt][1], bl[nt][1], acc);
                    #pragma unroll
                    for (int r = 0; r < 4; ++r)
                        Act[(t*16 + q*4 + r) * ASTR + nt*16 + li] = fmaxf(acc[r], 0.f);
                }
            }
        }
        __syncthreads();

        // ---- L2: Act -> Act ----
        {
            s16x8 bh[3][2], bl[3][2]; float bs[3];
            #pragma unroll
            for (int nt = 0; nt < 3; ++nt) {
                bs[nt] = BIAS[160 + nt*16 + li];
                #pragma unroll
                for (int ks = 0; ks < 2; ++ks) {
                    int wi = (160 + nt*16 + li) * 64 + ks*32 + q*8;
                    bh[nt][ks] = ld8u(WH + wi);
                    bl[nt][ks] = ld8u(WL + wi);
                }
            }
            #pragma unroll
            for (int t = 0; t < 2; ++t) {
                const float* ap = Act + (t*16 + li) * ASTR;
                float a0[8], a1[8];
                *(float4*)(a0)   = *(const float4*)(ap + q*8);
                *(float4*)(a0+4) = *(const float4*)(ap + q*8 + 4);
                *(float4*)(a1)   = *(const float4*)(ap + 32 + q*8);
                *(float4*)(a1+4) = *(const float4*)(ap + 32 + q*8 + 4);
                s16x8 ah0, al0, ah1, al1;
                split8(a0, ah0, al0); split8(a1, ah1, al1);
                #pragma unroll
                for (int nt = 0; nt < 3; ++nt) {
                    f32x4 acc = {bs[nt], bs[nt], bs[nt], bs[nt]};
                    acc = mm3(ah0, al0, bh[nt][0], bl[nt][0], acc);
                    acc = mm3(ah1, al1, bh[nt][1], bl[nt][1], acc);
                    #pragma unroll
                    for (int r = 0; r < 4; ++r)
                        Act[(t*16 + q*4 + r) * ASTR + nt*16 + li] = fmaxf(acc[r], 0.f);
                }
            }
        }
        __syncthreads();

        // ---- L3 + softmax*iab -> out ----
        {
            s16x8 bh[2][2], bl[2][2]; float bs[2];
            #pragma unroll
            for (int nt = 0; nt < 2; ++nt) {
                bs[nt] = BIAS[208 + nt*16 + li];
                #pragma unroll
                for (int ks = 0; ks < 2; ++ks) {
                    int wi = (208 + nt*16 + li) * 64 + ks*32 + q*8;
                    bh[nt][ks] = ld8u(WH + wi);
                    bl[nt][ks] = ld8u(WL + wi);
                }
            }
            #pragma unroll
            for (int t = 0; t < 2; ++t) {
                const float* ap = Act + (t*16 + li) * ASTR;
                float a0[8], a1[8];
                *(float4*)(a0)   = *(const float4*)(ap + q*8);
                *(float4*)(a0+4) = *(const float4*)(ap + q*8 + 4);
                *(float4*)(a1)   = *(const float4*)(ap + 32 + q*8);
                *(float4*)(a1+4) = *(const float4*)(ap + 32 + q*8 + 4);
                s16x8 ah0, al0, ah1, al1;
                split8(a0, ah0, al0); split8(a1, ah1, al1);
                f32x4 acc0 = {bs[0], bs[0], bs[0], bs[0]};
                f32x4 acc1 = {bs[1], bs[1], bs[1], bs[1]};
                acc0 = mm3(ah0, al0, bh[0][0], bl[0][0], acc0);
                acc0 = mm3(ah1, al1, bh[0][1], bl[0][1], acc0);
                acc1 = mm3(ah0, al0, bh[1][0], bl[1][0], acc1);
                acc1 = mm3(ah1, al1, bh[1][1], bl[1][1], acc1);
                #pragma unroll
                for (int r = 0; r < 4; ++r) {
                    float v0 = acc0[r], v1 = acc1[r];
                    float m = fmaxf(v0, v1);
                    m = fmaxf(m, __shfl_xor(m, 1));
                    m = fmaxf(m, __shfl_xor(m, 2));
                    m = fmaxf(m, __shfl_xor(m, 4));
                    m = fmaxf(m, __shfl_xor(m, 8));
                    float e0 = __expf(v0 - m);
                    float e1 = __expf(v1 - m);
                    float sum = e0 + e1;
                    sum += __shfl_xor(sum, 1);
                    sum += __shfl_xor(sum, 2);
                    sum += __shfl_xor(sum, 4);
                    sum += __shfl_xor(sum, 8);
                    int lrow = t*16 + q*4 + r;
                    float iv = ia[lrow * 10 + s];
                    float sc = __fdividef(iv, sum);
                    float* op = out + (size_t)(R0 + lrow) * ODIM + s*22;
                    op[li] = e0 * sc;
                    if (li < 6) op[16 + li] = e1 * sc;
                }
            }
        }
        __syncthreads();
    }
}

extern "C" void kernel_launch(void* const* d_in, const int* in_sizes, int n_in,
                              void* d_out, int out_size, void* d_ws, size_t ws_size,
                              hipStream_t stream)
{
    (void)n_in; (void)out_size; (void)ws_size;
    const float* x   = (const float*)d_in[0];
    const float* bW1 = (const float*)d_in[1];
    const float* bb1 = (const float*)d_in[2];
    const float* bW2 = (const float*)d_in[3];
    const float* bb2 = (const float*)d_in[4];
    const float* bW3 = (const float*)d_in[5];
    const float* bb3 = (const float*)d_in[6];
    const float* sW1 = (const float*)d_in[7];
    const float* sb1 = (const float*)d_in[8];
    const float* sW2 = (const float*)d_in[9];
    const float* sb2 = (const float*)d_in[10];
    const float* sW3 = (const float*)d_in[11];
    const float* sb3 = (const float*)d_in[12];
    float* outp = (float*)d_out;

    unsigned short* WH = (unsigned short*)d_ws;
    unsigned short* WL = WH + 15360;
    float* BIAS = (float*)(WH + 30720);

    prep_w<<<61, 256, 0, stream>>>(bW1, bW2, bW3, sW1, sW2, sW3,
                                   bb1, bb2, bb3, sb1, sb2, sb3, WH, WL, BIAS);

    const int rows = in_sizes[0] / XDIM;            // 262144
    ran_mfma<<<rows / ROWS, 64, 0, stream>>>(x, WH, WL, BIAS, outp);
}

// Round 5
// 535.980 us; speedup vs baseline: 2.3600x; 1.6188x over previous
//
#include <hip/hip_runtime.h>

typedef __attribute__((ext_vector_type(4))) float f32x4;
typedef __attribute__((ext_vector_type(8))) short s16x8;
typedef unsigned int u32;

#define XDIM 440
#define ODIM 220
#define RPB  32          // rows per block
#define TPB  128         // 2 waves; wave w owns rows [w*16, w*16+16)
#define XSW  52          // xsl row stride (u32): 16B-aligned rows, octet-tiled banks
#define AW   68          // Act row stride (u32): 16B-aligned rows, octet-tiled banks

// ---------- packed split helpers (fp32 -> bf16hi|bf16lo in one u32) ----------
__device__ __forceinline__ u32 cvtpk(float a, float b){
    u32 r; asm("v_cvt_pk_bf16_f32 %0, %1, %2" : "=v"(r) : "v"(a), "v"(b)); return r;
}
__device__ __forceinline__ u32 permb(u32 a, u32 b, u32 s){ return __builtin_amdgcn_perm(a, b, s); }

__device__ __forceinline__ u32 packf(float v){
    u32 h = cvtpk(v, v);                                  // [15:0] = bf16(v)
    float hf = __builtin_bit_cast(float, h << 16);
    u32 lo = cvtpk(v - hf, v - hf);                       // v-hf exact (Sterbenz)
    return permb(h, lo, 0x05040100u);                     // [31:16]=hi [15:0]=lo
}

__device__ __forceinline__ void split8pk(const float* v, s16x8& h, s16x8& l){
    uint4 hu, lu; u32* hp = (u32*)&hu; u32* lp = (u32*)&lu;
    #pragma unroll
    for (int j = 0; j < 4; ++j){
        u32 hk = cvtpk(v[2*j], v[2*j+1]);
        float h0 = __builtin_bit_cast(float, hk << 16);
        float h1 = __builtin_bit_cast(float, hk & 0xFFFF0000u);
        lp[j] = cvtpk(v[2*j] - h0, v[2*j+1] - h1);
        hp[j] = hk;
    }
    h = __builtin_bit_cast(s16x8, hu);
    l = __builtin_bit_cast(s16x8, lu);
}

// 8 packed u32 -> (hi, lo) s16x8 fragments, 1 v_perm per output reg
__device__ __forceinline__ void buildfrag(const u32* p, s16x8& h, s16x8& l){
    uint4 U0 = *(const uint4*)p;
    uint4 U1 = *(const uint4*)(p + 4);
    u32 u0=U0.x,u1=U0.y,u2=U0.z,u3=U0.w,u4=U1.x,u5=U1.y,u6=U1.z,u7=U1.w;
    uint4 hu, lu;
    hu.x = permb(u1,u0,0x07060302u); lu.x = permb(u1,u0,0x05040100u);
    hu.y = permb(u3,u2,0x07060302u); lu.y = permb(u3,u2,0x05040100u);
    hu.z = permb(u5,u4,0x07060302u); lu.z = permb(u5,u4,0x05040100u);
    hu.w = permb(u7,u6,0x07060302u); lu.w = permb(u7,u6,0x05040100u);
    h = __builtin_bit_cast(s16x8, hu);
    l = __builtin_bit_cast(s16x8, lu);
}

__device__ __forceinline__ s16x8 ld8u(const unsigned short* p){ return *(const s16x8*)p; }

// D += A*B, split-bf16: AhBh + AhBl + AlBh (AlBl dropped, ~2^-18)
__device__ __forceinline__ f32x4 mm3(s16x8 ah, s16x8 al, s16x8 bh, s16x8 bl, f32x4 c){
    c = __builtin_amdgcn_mfma_f32_16x16x32_bf16(ah, bh, c, 0, 0, 0);
    c = __builtin_amdgcn_mfma_f32_16x16x32_bf16(ah, bl, c, 0, 0, 0);
    c = __builtin_amdgcn_mfma_f32_16x16x32_bf16(al, bh, c, 0, 0, 0);
    return c;
}

// ---------- weight prep: split to bf16 hi/lo, pad to [240][64] ----------
// rows: [0..47]=bW1 [48..95]=bW2 [96..111]=bW3 [112..159]=sW1 [160..207]=sW2 [208..239]=sW3
__device__ __forceinline__ unsigned short bf_rne(float f){
    unsigned u = __builtin_bit_cast(unsigned, f);
    return (unsigned short)((u + 0x7FFFu + ((u >> 16) & 1u)) >> 16);
}

__global__ void prep_w(const float* __restrict__ bW1, const float* __restrict__ bW2,
                       const float* __restrict__ bW3, const float* __restrict__ sW1,
                       const float* __restrict__ sW2, const float* __restrict__ sW3,
                       const float* __restrict__ bb1, const float* __restrict__ bb2,
                       const float* __restrict__ bb3, const float* __restrict__ sb1,
                       const float* __restrict__ sb2, const float* __restrict__ sb3,
                       unsigned short* __restrict__ WH, unsigned short* __restrict__ WL,
                       float* __restrict__ BIAS)
{
    int i = blockIdx.x * 256 + threadIdx.x;
    if (i < 15360) {
        int n = i >> 6, k = i & 63;
        float w = 0.f;
        if      (n < 48)  { int r = n;     if (r < 40 && k < 40) w = bW1[r*40+k]; }
        else if (n < 96)  { int r = n-48;  if (r < 40 && k < 40) w = bW2[r*40+k]; }
        else if (n < 112) { int r = n-96;  if (r < 10 && k < 40) w = bW3[r*40+k]; }
        else if (n < 160) { int r = n-112; if (r < 41 && k < 41) w = sW1[r*41+k]; }
        else if (n < 208) { int r = n-160; if (r < 41 && k < 41) w = sW2[r*41+k]; }
        else              { int r = n-208; if (r < 22 && k < 41) w = sW3[r*41+k]; }
        unsigned short h = bf_rne(w);
        float hf = __builtin_bit_cast(float, ((unsigned)h) << 16);
        WH[i] = h; WL[i] = bf_rne(w - hf);
    } else if (i < 15600) {
        int n = i - 15360;
        float b;
        if      (n < 48)  b = (n     < 40) ? bb1[n]     : 0.f;
        else if (n < 96)  b = (n-48  < 40) ? bb2[n-48]  : 0.f;
        else if (n < 112) b = (n-96  < 10) ? bb3[n-96]  : -1e30f;
        else if (n < 160) b = (n-112 < 41) ? sb1[n-112] : 0.f;
        else if (n < 208) b = (n-160 < 41) ? sb2[n-160] : 0.f;
        else              b = (n-208 < 22) ? sb3[n-208] : -1e30f;
        BIAS[n] = b;
    }
}

// ---------- slot staging: 32 rows x 40 cols, coalesced float4, pre-split ----------
__device__ __forceinline__ void stage_load(const float* __restrict__ x, int R0, int S,
                                           int tid, float4* pf){
    #pragma unroll
    for (int it = 0; it < 3; ++it){
        int f = tid + TPB*it;
        if (f < 320){
            int r = f/10, c4 = f - r*10;
            pf[it] = *(const float4*)(x + (size_t)(R0+r)*XDIM + 40 + S*40 + c4*4);
        }
    }
}
__device__ __forceinline__ void stage_write(u32 (*xb)[XSW], const float* iap, int S,
                                            int tid, const float4* pf){
    #pragma unroll
    for (int it = 0; it < 3; ++it){
        int f = tid + TPB*it;
        if (f < 320){
            int r = f/10, c4 = f - r*10;
            uint4 pk;
            pk.x = packf(pf[it].x); pk.y = packf(pf[it].y);
            pk.z = packf(pf[it].z); pk.w = packf(pf[it].w);
            *(uint4*)&xb[r][c4*4] = pk;
        }
    }
    if (tid < RPB) xb[tid][40] = packf(iap[tid*10 + S]);   // iab input (k=40)
}

__global__ __launch_bounds__(TPB, 2) void ran2(
    const float* __restrict__ x,
    const unsigned short* __restrict__ WH,
    const unsigned short* __restrict__ WL,
    const float* __restrict__ BIAS,
    float* __restrict__ out)
{
    __shared__ u32   xsl[2][RPB][XSW];   // per-slot inputs, packed split, dbuf (13.0 KB)
    __shared__ u32   Act[RPB][AW];       // activations, packed split (8.5 KB)
    __shared__ float ia[RPB][10];        // big-net softmax (1.25 KB)
    __shared__ float ob[RPB][ODIM];      // output staging (27.5 KB)

    const int tid  = threadIdx.x;
    const int l    = tid & 63;
    const int w    = tid >> 6;
    const int q    = l >> 4;
    const int li   = l & 15;
    const int w16  = w * 16;
    const int R0   = blockIdx.x * RPB;
    const int arow = w16 + li;           // this lane's A-fragment row (local)

    // one-time zero of pad regions (xsl cols 40..51 both buffers; Act cols 48..67)
    for (int i = tid; i < 2*RPB*(XSW-40); i += TPB){
        int b = i / (RPB*(XSW-40)), k = i % (RPB*(XSW-40));
        xsl[b][k/(XSW-40)][40 + k%(XSW-40)] = 0u;
    }
    for (int i = tid; i < RPB*(AW-48); i += TPB)
        Act[i/(AW-48)][48 + i%(AW-48)] = 0u;
    __syncthreads();

    // ================= BIG NET (Act is wave-private: no barriers) =================
    {   // L1: x[:,0:40] -> Act
        s16x8 th[3][2], tl[3][2]; float tb[3];
        #pragma unroll
        for (int nt=0; nt<3; ++nt){
            tb[nt] = BIAS[nt*16+li];
            #pragma unroll
            for (int ks=0; ks<2; ++ks){
                th[nt][ks] = ld8u(WH + (nt*16+li)*64 + ks*32 + q*8);
                tl[nt][ks] = ld8u(WL + (nt*16+li)*64 + ks*32 + q*8);
            }
        }
        const float* xp = x + (size_t)(R0 + arow) * XDIM;
        float a0[8], a1[8];
        *(float4*)(a0)   = *(const float4*)(xp + q*8);
        *(float4*)(a0+4) = *(const float4*)(xp + q*8 + 4);
        if (q == 0){
            *(float4*)(a1)   = *(const float4*)(xp + 32);
            *(float4*)(a1+4) = *(const float4*)(xp + 36);
        } else {
            #pragma unroll
            for (int j=0;j<8;++j) a1[j] = 0.f;
        }
        s16x8 ah0,al0,ah1,al1;
        split8pk(a0, ah0, al0); split8pk(a1, ah1, al1);
        #pragma unroll
        for (int nt=0; nt<3; ++nt){
            f32x4 acc = {tb[nt],tb[nt],tb[nt],tb[nt]};
            acc = mm3(ah0,al0, th[nt][0], tl[nt][0], acc);
            acc = mm3(ah1,al1, th[nt][1], tl[nt][1], acc);
            #pragma unroll
            for (int r=0;r<4;++r)
                Act[w16+q*4+r][nt*16+li] = packf(fmaxf(acc[r],0.f));
        }
    }
    {   // L2: Act -> Act
        s16x8 th[3][2], tl[3][2]; float tb[3];
        #pragma unroll
        for (int nt=0; nt<3; ++nt){
            tb[nt] = BIAS[48+nt*16+li];
            #pragma unroll
            for (int ks=0; ks<2; ++ks){
                th[nt][ks] = ld8u(WH + (48+nt*16+li)*64 + ks*32 + q*8);
                tl[nt][ks] = ld8u(WL + (48+nt*16+li)*64 + ks*32 + q*8);
            }
        }
        s16x8 ah0,al0,ah1,al1;
        const u32* ap = &Act[arow][0];
        buildfrag(ap + q*8, ah0, al0);
        buildfrag(ap + 32 + q*8, ah1, al1);
        #pragma unroll
        for (int nt=0; nt<3; ++nt){
            f32x4 acc = {tb[nt],tb[nt],tb[nt],tb[nt]};
            acc = mm3(ah0,al0, th[nt][0], tl[nt][0], acc);
            acc = mm3(ah1,al1, th[nt][1], tl[nt][1], acc);
            #pragma unroll
            for (int r=0;r<4;++r)
                Act[w16+q*4+r][nt*16+li] = packf(fmaxf(acc[r],0.f));
        }
    }
    {   // L3 + softmax -> ia
        s16x8 th[2], tl[2]; float tb = BIAS[96+li];
        th[0] = ld8u(WH + (96+li)*64 + q*8);      tl[0] = ld8u(WL + (96+li)*64 + q*8);
        th[1] = ld8u(WH + (96+li)*64 + 32 + q*8); tl[1] = ld8u(WL + (96+li)*64 + 32 + q*8);
        s16x8 ah0,al0,ah1,al1;
        const u32* ap = &Act[arow][0];
        buildfrag(ap + q*8, ah0, al0);
        buildfrag(ap + 32 + q*8, ah1, al1);
        f32x4 acc = {tb,tb,tb,tb};
        acc = mm3(ah0,al0, th[0], tl[0], acc);
        acc = mm3(ah1,al1, th[1], tl[1], acc);
        #pragma unroll
        for (int r=0;r<4;++r){
            float v = acc[r];
            float m = v;
            m = fmaxf(m, __shfl_xor(m,1)); m = fmaxf(m, __shfl_xor(m,2));
            m = fmaxf(m, __shfl_xor(m,4)); m = fmaxf(m, __shfl_xor(m,8));
            float e = __expf(v - m);
            float sum = e;
            sum += __shfl_xor(sum,1); sum += __shfl_xor(sum,2);
            sum += __shfl_xor(sum,4); sum += __shfl_xor(sum,8);
            float p = __fdividef(e, sum);
            if (li < 10) ia[w16+q*4+r][li] = p;
        }
    }
    __syncthreads();   // ia visible (stage reads it cross-wave)

    // hoist small-net weights: 8 tiles x 2 ks x (h,l) = 128 VGPR, reused 10x
    s16x8 sh[8][2], sl[8][2]; float sb[8];
    {
        const int base[8] = {112,128,144, 160,176,192, 208,224};
        #pragma unroll
        for (int t2=0;t2<8;++t2){
            int n = base[t2] + li;
            sb[t2] = BIAS[n];
            #pragma unroll
            for (int ks=0;ks<2;++ks){
                sh[t2][ks] = ld8u(WH + n*64 + ks*32 + q*8);
                sl[t2][ks] = ld8u(WL + n*64 + ks*32 + q*8);
            }
        }
    }

    // stage slot 0
    {
        float4 pf[3];
        stage_load(x, R0, 0, tid, pf);
        stage_write(xsl[0], &ia[0][0], 0, tid, pf);
    }
    __syncthreads();

    // ================= SMALL NET: 10 slots, 1 barrier each =================
    int cur = 0;
    #pragma unroll 1
    for (int s = 0; s < 10; ++s){
        float4 pf[3];
        if (s < 9) stage_load(x, R0, s+1, tid, pf);      // early issue (T14)

        // ---- L1: xsl[cur] -> Act ----
        {
            s16x8 ah0,al0,ah1,al1;
            const u32* xr = &xsl[cur][arow][0];
            buildfrag(xr + q*8, ah0, al0);
            if (q < 2) buildfrag(xr + 32 + q*8, ah1, al1);
            else { uint4 z = {0,0,0,0}; ah1 = __builtin_bit_cast(s16x8, z); al1 = ah1; }
            #pragma unroll
            for (int nt=0; nt<3; ++nt){
                f32x4 acc = {sb[nt],sb[nt],sb[nt],sb[nt]};
                acc = mm3(ah0,al0, sh[nt][0], sl[nt][0], acc);
                acc = mm3(ah1,al1, sh[nt][1], sl[nt][1], acc);
                #pragma unroll
                for (int r=0;r<4;++r)
                    Act[w16+q*4+r][nt*16+li] = packf(fmaxf(acc[r],0.f));
            }
        }
        // write next slot's tile into the free buffer (hidden under compute)
        if (s < 9) stage_write(xsl[cur^1], &ia[0][0], s+1, tid, pf);

        // ---- L2: Act -> Act ----
        {
            s16x8 ah0,al0,ah1,al1;
            const u32* ap = &Act[arow][0];
            buildfrag(ap + q*8, ah0, al0);
            buildfrag(ap + 32 + q*8, ah1, al1);
            #pragma unroll
            for (int nt=0; nt<3; ++nt){
                f32x4 acc = {sb[3+nt],sb[3+nt],sb[3+nt],sb[3+nt]};
                acc = mm3(ah0,al0, sh[3+nt][0], sl[3+nt][0], acc);
                acc = mm3(ah1,al1, sh[3+nt][1], sl[3+nt][1], acc);
                #pragma unroll
                for (int r=0;r<4;++r)
                    Act[w16+q*4+r][nt*16+li] = packf(fmaxf(acc[r],0.f));
            }
        }
        // ---- L3 + softmax * iab -> ob ----
        {
            s16x8 ah0,al0,ah1,al1;
            const u32* ap = &Act[arow][0];
            buildfrag(ap + q*8, ah0, al0);
            buildfrag(ap + 32 + q*8, ah1, al1);
            f32x4 a6 = {sb[6],sb[6],sb[6],sb[6]};
            f32x4 a7 = {sb[7],sb[7],sb[7],sb[7]};
            a6 = mm3(ah0,al0, sh[6][0], sl[6][0], a6);
            a6 = mm3(ah1,al1, sh[6][1], sl[6][1], a6);
            a7 = mm3(ah0,al0, sh[7][0], sl[7][0], a7);
            a7 = mm3(ah1,al1, sh[7][1], sl[7][1], a7);
            #pragma unroll
            for (int r=0;r<4;++r){
                float v0 = a6[r], v1 = a7[r];
                float m = fmaxf(v0, v1);
                m = fmaxf(m, __shfl_xor(m,1)); m = fmaxf(m, __shfl_xor(m,2));
                m = fmaxf(m, __shfl_xor(m,4)); m = fmaxf(m, __shfl_xor(m,8));
                float e0 = __expf(v0 - m), e1 = __expf(v1 - m);
                float sum = e0 + e1;
                sum += __shfl_xor(sum,1); sum += __shfl_xor(sum,2);
                sum += __shfl_xor(sum,4); sum += __shfl_xor(sum,8);
                int lr = w16 + q*4 + r;
                float sc = __fdividef(ia[lr][s], sum);
                ob[lr][s*22 + li] = e0 * sc;
                if (li < 6) ob[lr][s*22 + 16 + li] = e1 * sc;
            }
        }
        __syncthreads();   // stage visible + Act/ob epoch boundary
        cur ^= 1;
    }

    // ================= coalesced output write =================
    #pragma unroll
    for (int it = 0; it < 14; ++it){
        int f = tid + TPB*it;
        if (f < 1760){
            int r = f/55, c4 = f - r*55;
            *(float4*)(out + (size_t)(R0+r)*ODIM + c4*4) = *(const float4*)&ob[r][c4*4];
        }
    }
}

extern "C" void kernel_launch(void* const* d_in, const int* in_sizes, int n_in,
                              void* d_out, int out_size, void* d_ws, size_t ws_size,
                              hipStream_t stream)
{
    (void)n_in; (void)out_size; (void)ws_size;
    const float* x   = (const float*)d_in[0];
    const float* bW1 = (const float*)d_in[1];
    const float* bb1 = (const float*)d_in[2];
    const float* bW2 = (const float*)d_in[3];
    const float* bb2 = (const float*)d_in[4];
    const float* bW3 = (const float*)d_in[5];
    const float* bb3 = (const float*)d_in[6];
    const float* sW1 = (const float*)d_in[7];
    const float* sb1 = (const float*)d_in[8];
    const float* sW2 = (const float*)d_in[9];
    const float* sb2 = (const float*)d_in[10];
    const float* sW3 = (const float*)d_in[11];
    const float* sb3 = (const float*)d_in[12];
    float* outp = (float*)d_out;

    unsigned short* WH = (unsigned short*)d_ws;
    unsigned short* WL = WH + 15360;
    float* BIAS = (float*)(WH + 30720);

    prep_w<<<61, 256, 0, stream>>>(bW1, bW2, bW3, sW1, sW2, sW3,
                                   bb1, bb2, bb3, sb1, sb2, sb3, WH, WL, BIAS);

    const int rows = in_sizes[0] / XDIM;            // 262144
    ran2<<<rows / RPB, TPB, 0, stream>>>(x, WH, WL, BIAS, outp);
}